// Round 1
// baseline (182.290 us; speedup 1.0000x reference)
//
#include <hip/hip_runtime.h>
#include <math.h>

constexpr int D_MODEL = 2048;
constexpr int NE      = 64;     // experts
constexpr int TOKENS  = 16384;  // 4*4096
constexpr int WAVES   = 8;      // waves per block
constexpr int KC      = 256;    // k-range per wave (2048/8)
constexpr int CH      = 16;     // floats per inner chunk

__global__ __launch_bounds__(512, 2)
void router_kernel(const float* __restrict__ X,
                   const float* __restrict__ W,
                   const float* __restrict__ B,
                   float* __restrict__ out) {
  // partial logits: [wave][token][expert], pad 65 -> bank = (l+e)%32, 2-way only (free)
  __shared__ float p_lds[WAVES][64][65];
  __shared__ int   i1_lds[64], i2_lds[64];
  __shared__ float p1_lds[64], p2_lds[64];

  const int t   = threadIdx.x;
  const int w   = t >> 6;          // wave id = k-chunk id
  const int l   = t & 63;          // lane = local token
  const int blk = blockIdx.x;
  const int tok = (blk << 6) + l;

  // wave-uniform copy of w so W/B addressing provably lands in SGPRs (s_load)
  const int wu = __builtin_amdgcn_readfirstlane(w);

  // ---- phase 1: partial logits over this wave's k-chunk ----
  float acc[NE];
#pragma unroll
  for (int e = 0; e < NE; ++e) acc[e] = 0.f;

  const float4* x4 = reinterpret_cast<const float4*>(X + (size_t)tok * D_MODEL + wu * KC);
  const float*  wb = W + wu * KC;

  float4 n0 = x4[0], n1 = x4[1], n2 = x4[2], n3 = x4[3];

  for (int c = 0; c < KC / CH; ++c) {
    float xv[CH];
    *reinterpret_cast<float4*>(&xv[0])  = n0;
    *reinterpret_cast<float4*>(&xv[4])  = n1;
    *reinterpret_cast<float4*>(&xv[8])  = n2;
    *reinterpret_cast<float4*>(&xv[12]) = n3;
    if (c < KC / CH - 1) {           // prefetch next x chunk
      n0 = x4[(c + 1) * 4 + 0];
      n1 = x4[(c + 1) * 4 + 1];
      n2 = x4[(c + 1) * 4 + 2];
      n3 = x4[(c + 1) * 4 + 3];
    }
    const float* wc = wb + c * CH;
#pragma unroll
    for (int e = 0; e < NE; ++e) {
      const float* wr = wc + e * D_MODEL;   // wave-uniform -> s_load_dwordx16
#pragma unroll
      for (int i = 0; i < CH; ++i)
        acc[e] = fmaf(xv[i], wr[i], acc[e]);
    }
  }

#pragma unroll
  for (int e = 0; e < NE; ++e) p_lds[w][l][e] = acc[e];
  __syncthreads();

  // ---- phase 2: reduce 8 partials; thread (w,l) -> experts 8w..8w+7 of token l ----
  float lg[8];
#pragma unroll
  for (int j = 0; j < 8; ++j) {
    const int e = (wu << 3) + j;
    float s = B[e];
#pragma unroll
    for (int q = 0; q < WAVES; ++q) s += p_lds[q][l][e];
    lg[j] = s;
  }
  __syncthreads();   // all reads of p_lds done before overwrite
#pragma unroll
  for (int j = 0; j < 8; ++j) p_lds[0][l][(w << 3) + j] = lg[j];
  __syncthreads();

  // ---- phase 3: per-token top-2 + softmax (wave 0; 1 token/lane) ----
  if (t < 64) {
    float m1 = -INFINITY, m2 = -INFINITY;
    int j1 = 0, j2 = 0;
    for (int e = 0; e < NE; ++e) {
      const float v = p_lds[0][t][e];
      if (v > m1) { m2 = m1; j2 = j1; m1 = v; j1 = e; }       // strict > :
      else if (v > m2) { m2 = v; j2 = e; }                    // ties keep lower index (lax.top_k)
    }
    const float e2  = expf(m2 - m1);
    const float inv = 1.0f / (1.0f + e2);
    i1_lds[t] = j1; i2_lds[t] = j2;
    p1_lds[t] = inv; p2_lds[t] = e2 * inv;
    // output 1: indices (as float32 values, concatenated after sf)
    float* oidx = out + (size_t)TOKENS * NE + (size_t)((blk << 6) + t) * 2;
    oidx[0] = (float)j1;
    oidx[1] = (float)j2;
  }
  __syncthreads();

  // ---- phase 4: coalesced sf tile write (full zeros + scattered probs inline) ----
  {
    const int tokl = t >> 3;           // 64 tokens x 8 threads each
    const int ecol = (t & 7) << 3;     // 8 experts per thread
    const int j1 = i1_lds[tokl], j2 = i2_lds[tokl];
    const float pa = p1_lds[tokl], pb = p2_lds[tokl];
    float v[8];
#pragma unroll
    for (int i = 0; i < 8; ++i) {
      const int e = ecol + i;
      v[i] = (e == j1) ? pa : ((e == j2) ? pb : 0.f);
    }
    float4* o4 = reinterpret_cast<float4*>(out + ((size_t)((blk << 6) + tokl) << 6) + ecol);
    o4[0] = make_float4(v[0], v[1], v[2], v[3]);
    o4[1] = make_float4(v[4], v[5], v[6], v[7]);
  }
}

extern "C" void kernel_launch(void* const* d_in, const int* in_sizes, int n_in,
                              void* d_out, int out_size, void* d_ws, size_t ws_size,
                              hipStream_t stream) {
  const float* X = (const float*)d_in[0];
  const float* W = (const float*)d_in[1];
  const float* B = (const float*)d_in[2];
  float* out = (float*)d_out;
  router_kernel<<<dim3(TOKENS / 64), dim3(512), 0, stream>>>(X, W, B, out);
}

// Round 2
// 55.409 us; speedup vs baseline: 3.2899x; 3.2899x over previous
//
#include <hip/hip_runtime.h>
#include <hip/hip_bf16.h>
#include <math.h>

constexpr int D      = 2048;
constexpr int NE     = 64;
constexpr int TOKENS = 16384;   // 4*4096
constexpr int TPB    = 32;      // tokens per block
constexpr int NWAVE  = 8;       // k-split waves per block
constexpr int KSLICE = D / NWAVE;   // 256 k per wave
constexpr int KC     = 32;      // k per MFMA

typedef __attribute__((ext_vector_type(8))) short bf16x8;
typedef __attribute__((ext_vector_type(4))) float f32x4;

static __device__ inline unsigned short f2bf_u(float x) {
  __hip_bfloat16 h = __float2bfloat16(x);   // RNE
  unsigned short u; __builtin_memcpy(&u, &h, 2); return u;
}
static __device__ inline float bfu2f(unsigned short u) {
  __hip_bfloat16 h; __builtin_memcpy(&h, &u, 2);
  return __bfloat162float(h);
}

// split 8 f32 into hi/lo bf16 fragments (exact: x = hi + lo + O(2^-26 x))
static __device__ inline void cvt_hilo(const float* f, bf16x8& hi, bf16x8& lo) {
#pragma unroll
  for (int j = 0; j < 8; ++j) {
    unsigned short h = f2bf_u(f[j]);
    float hf = bfu2f(h);
    unsigned short lw = f2bf_u(f[j] - hf);
    hi[j] = (short)h;
    lo[j] = (short)lw;
  }
}

__global__ __launch_bounds__(512, 4)
void router_mfma(const float* __restrict__ X,
                 const float* __restrict__ W,
                 const float* __restrict__ bias,
                 float* __restrict__ out) {
  // k-split partials: [wave][token][expert], pad 65 (write aliasing <= 4-way, read 2-way)
  __shared__ float red[NWAVE][TPB][NE + 1];   // 66.6 KB
  __shared__ float lgb[TPB][NE + 1];          //  8.3 KB
  __shared__ int   i1s[TPB], i2s[TPB];
  __shared__ float p1s[TPB], p2s[TPB];

  const int t   = threadIdx.x;
  const int w   = t >> 6;        // wave id = k-slice
  const int l   = t & 63;
  const int lm  = l & 15;        // M-row / N-col within tile
  const int lk  = l >> 4;        // k-group (0..3) -> k offset lk*8
  const int blk = blockIdx.x;
  const int tok0 = blk * TPB;

  f32x4 acc[2][4];
#pragma unroll
  for (int m = 0; m < 2; ++m)
#pragma unroll
    for (int n = 0; n < 4; ++n) acc[m][n] = (f32x4){0.f, 0.f, 0.f, 0.f};

  const int kslice0 = w * KSLICE;

  for (int kc = 0; kc < KSLICE / KC; ++kc) {
    const int kb = kslice0 + kc * KC + lk * 8;   // this lane's 8-k group

    // ---- B fragments: W^T tile, 4 n-tiles, hi/lo (B[k][n]: n=lm, k=lk*8+j) ----
    bf16x8 bh[4], bl[4];
#pragma unroll
    for (int n = 0; n < 4; ++n) {
      const float* wp = W + (size_t)(n * 16 + lm) * D + kb;
      float f[8];
      *reinterpret_cast<float4*>(&f[0]) = *reinterpret_cast<const float4*>(wp);
      *reinterpret_cast<float4*>(&f[4]) = *reinterpret_cast<const float4*>(wp + 4);
      cvt_hilo(f, bh[n], bl[n]);
    }

    // ---- A fragments per m-tile (A[m][k]: m=lm, k=lk*8+j), then 16 MFMAs ----
#pragma unroll
    for (int m = 0; m < 2; ++m) {
      const float* xp = X + (size_t)(tok0 + m * 16 + lm) * D + kb;
      float f[8];
      *reinterpret_cast<float4*>(&f[0]) = *reinterpret_cast<const float4*>(xp);
      *reinterpret_cast<float4*>(&f[4]) = *reinterpret_cast<const float4*>(xp + 4);
      bf16x8 ah, al;
      cvt_hilo(f, ah, al);
#pragma unroll
      for (int n = 0; n < 4; ++n) {
        acc[m][n] = __builtin_amdgcn_mfma_f32_16x16x32_bf16(ah, bh[n], acc[m][n], 0, 0, 0);
        acc[m][n] = __builtin_amdgcn_mfma_f32_16x16x32_bf16(ah, bl[n], acc[m][n], 0, 0, 0);
        acc[m][n] = __builtin_amdgcn_mfma_f32_16x16x32_bf16(al, bh[n], acc[m][n], 0, 0, 0);
        acc[m][n] = __builtin_amdgcn_mfma_f32_16x16x32_bf16(al, bl[n], acc[m][n], 0, 0, 0);
      }
    }
  }

  // ---- stash k-partials: C row = lk*4 + j (token), col = lm (expert)  [m89 layout] ----
#pragma unroll
  for (int m = 0; m < 2; ++m)
#pragma unroll
    for (int n = 0; n < 4; ++n)
#pragma unroll
      for (int j = 0; j < 4; ++j)
        red[w][m * 16 + lk * 4 + j][n * 16 + lm] = acc[m][n][j];
  __syncthreads();

  // ---- cross-wave reduce + bias: 512 thr x 4 outputs each ----
  {
    const int tok = t >> 4;
    const int e0  = (t & 15) * 4;
#pragma unroll
    for (int q = 0; q < 4; ++q) {
      const int e = e0 + q;
      float s = bias[e];
#pragma unroll
      for (int ww = 0; ww < NWAVE; ++ww) s += red[ww][tok][e];
      lgb[tok][e] = s;
    }
  }
  __syncthreads();

  // ---- top-2 + softmax weights (threads 0..31, one token each) ----
  if (t < TPB) {
    float m1 = -INFINITY, m2 = -INFINITY;
    int j1 = 0, j2 = 0;
    for (int e = 0; e < NE; ++e) {
      const float v = lgb[t][e];
      if (v > m1) { m2 = m1; j2 = j1; m1 = v; j1 = e; }     // strict >: lax.top_k tie-break
      else if (v > m2) { m2 = v; j2 = e; }
    }
    const float e2  = expf(m2 - m1);
    const float inv = 1.0f / (1.0f + e2);
    i1s[t] = j1; i2s[t] = j2;
    p1s[t] = inv; p2s[t] = e2 * inv;
    float* oidx = out + (size_t)TOKENS * NE + (size_t)(tok0 + t) * 2;
    oidx[0] = (float)j1;
    oidx[1] = (float)j2;
  }
  __syncthreads();

  // ---- coalesced sf write: thread -> (token = t>>4, experts e0..e0+3) ----
  {
    const int tok = t >> 4;
    const int e0  = (t & 15) * 4;
    const int j1 = i1s[tok], j2 = i2s[tok];
    const float pa = p1s[tok], pb = p2s[tok];
    float vv[4];
#pragma unroll
    for (int q = 0; q < 4; ++q) {
      const int e = e0 + q;
      vv[q] = (e == j1) ? pa : ((e == j2) ? pb : 0.f);
    }
    *reinterpret_cast<float4*>(out + (size_t)(tok0 + tok) * NE + e0) =
        make_float4(vv[0], vv[1], vv[2], vv[3]);
  }
}

extern "C" void kernel_launch(void* const* d_in, const int* in_sizes, int n_in,
                              void* d_out, int out_size, void* d_ws, size_t ws_size,
                              hipStream_t stream) {
  const float* X = (const float*)d_in[0];
  const float* W = (const float*)d_in[1];
  const float* B = (const float*)d_in[2];
  float* out = (float*)d_out;
  router_mfma<<<dim3(TOKENS / TPB), dim3(512), 0, stream>>>(X, W, B, out);
}